// Round 2
// baseline (948.726 us; speedup 1.0000x reference)
//
#include <hip/hip_runtime.h>
#include <stdint.h>

#define T_ 512
#define D_ 256
#define N_ 8192
#define NHEAD 16
#define SCALE_ 0.011048543456039806f   // 8192^-0.5
#define INV2PI 0.15915493667125702f

typedef __attribute__((ext_vector_type(8))) short bf16x8;
typedef __attribute__((ext_vector_type(4))) float f32x4;

__device__ __forceinline__ unsigned short f2bf(float x) {
  union { float f; unsigned u; } v; v.f = x;
  unsigned r = v.u + 0x7fffu + ((v.u >> 16) & 1u);   // RNE
  return (unsigned short)(r >> 16);
}

__device__ __forceinline__ void async16(const void* g, void* l) {
  __builtin_amdgcn_global_load_lds(
      (const __attribute__((address_space(1))) unsigned int*)g,
      (__attribute__((address_space(3))) unsigned int*)l,
      16, 0, 0);
}

// ---- swizzled direct staging: 128x32 bf16 tile, row-major source.
// LDS layout [128][32] linear (DMA requires), but LDS block b of row r holds
// GLOBAL block b ^ ((r>>1)&3). Fragment reads XOR-compensate -> conflict-free.
__device__ __forceinline__ void stage_direct(const unsigned short* __restrict__ g,
                                             int ld, unsigned short* lds, int t) {
  const int row = t >> 2, b = t & 3;
  const int g1 = (b ^ ((row >> 1) & 3)) * 8;
  async16(g + (size_t)row * ld + g1, lds + row * 32 + b * 8);
  const int row2 = row + 64;
  const int g2 = (b ^ ((row2 >> 1) & 3)) * 8;
  async16(g + (size_t)row2 * ld + g2, lds + row2 * 32 + b * 8);
}

// ---- fp32 row-major staging with fused scale + strict-tril mask (scores A operand)
__device__ __forceinline__ void stage_sc(const float* __restrict__ g, int gi0, int gk0,
                                         unsigned short* lds, int t) {
  const int row = t >> 2, c8 = (t & 3) * 8;
  #pragma unroll
  for (int rr = 0; rr < 2; rr++) {
    const int r = row + rr * 64;
    const float* p = g + (size_t)r * T_ + c8;
    float4 x = *(const float4*)p, y = *(const float4*)(p + 4);
    float f[8] = {x.x, x.y, x.z, x.w, y.x, y.y, y.z, y.w};
    const int gi = gi0 + r;
    __attribute__((aligned(16))) unsigned short u[8];
    #pragma unroll
    for (int e = 0; e < 8; e++) {
      float v = ((gk0 + c8 + e) < gi) ? f[e] * SCALE_ : 0.f;
      u[e] = f2bf(v);
    }
    *(uint4*)(lds + r * 40 + c8) = *(const uint4*)u;
  }
}

// One BK=32 step: wave (wr,wc) computes 64x64 of the 128x128 C tile.
// SWA/SWB: operand uses swizzled-[128][32] layout (else padded-[128][40]).
template<bool SWA, bool SWB>
__device__ __forceinline__ void mfma_step(const unsigned short* as, const unsigned short* bs,
                                          int wr, int wc, int lane, f32x4 acc[4][4]) {
  const int j8 = lane >> 4, rl = lane & 15;
  const int swz = (j8 ^ ((rl >> 1) & 3)) * 8;   // row base %16==0 -> s(row)=(rl>>1)&3
  const int pad = j8 * 8;
  bf16x8 a[4], b[4];
  #pragma unroll
  for (int i = 0; i < 4; i++) {
    int r = wr * 64 + i * 16 + rl;
    a[i] = SWA ? *(const bf16x8*)(as + r * 32 + swz)
               : *(const bf16x8*)(as + r * 40 + pad);
  }
  #pragma unroll
  for (int j = 0; j < 4; j++) {
    int r = wc * 64 + j * 16 + rl;
    b[j] = SWB ? *(const bf16x8*)(bs + r * 32 + swz)
               : *(const bf16x8*)(bs + r * 40 + pad);
  }
  #pragma unroll
  for (int i = 0; i < 4; i++)
    #pragma unroll
    for (int j = 0; j < 4; j++)
      acc[i][j] = __builtin_amdgcn_mfma_f32_16x16x32_bf16(a[i], b[j], acc[i][j], 0, 0, 0);
}

// ---------------- Kernel 1: fused rope -> QR (row-major) AND QRT (transposed) ----------------
// 64x64 tile per block through XOR-swizzled LDS: element (r,c) stored at tile[r][c ^ (r&56)].
// Both write phases emit 128B-contiguous global runs; LDS conflict-free (bank = swz-col only).
__global__ __launch_bounds__(256) void rope2_kernel(
    const float* __restrict__ Q, unsigned short* __restrict__ QR,
    unsigned short* __restrict__ QRT)
{
  __shared__ unsigned short tile[64][64];
  const int tid = threadIdx.x;
  const int n0 = blockIdx.x * 64, t0 = blockIdx.y * 64, h = blockIdx.z;
  const float* src = Q + ((size_t)h * T_ + t0) * N_ + n0;
  #pragma unroll
  for (int p = 0; p < 4; p++) {                        // 1024 slots: 64 rows x 16 x (4 f32)
    const int slot = tid + p * 256;
    const int row = slot >> 4, c4 = (slot & 15) * 4;
    float4 v = *(const float4*)(src + (size_t)row * N_ + c4);
    const float ft = (float)(t0 + row);
    __attribute__((aligned(8))) unsigned short u[4];
    #pragma unroll
    for (int pp = 0; pp < 2; pp++) {
      const int m = ((n0 + c4) >> 1) + pp;             // floor(idx/2)
      float f = exp2f((float)m * (-1.0f / 256.0f)) * INV2PI;
      float r = ft * f;
      r = r - floorf(r);                               // phases mod 1
      float cs = __builtin_amdgcn_cosf(r);             // cos(2*pi*r)
      float sn = __builtin_amdgcn_sinf(r);
      float ev = (pp == 0) ? v.x : v.z;
      float od = (pp == 0) ? v.y : v.w;
      u[2 * pp]     = f2bf(ev * cs - od * sn);
      u[2 * pp + 1] = f2bf(od * cs + ev * sn);
    }
    *(uint2*)(&tile[row][c4 ^ (row & 56)]) = *(const uint2*)u;
  }
  __syncthreads();
  unsigned short* qr = QR + ((size_t)h * T_ + t0) * N_ + n0;
  #pragma unroll
  for (int p = 0; p < 2; p++) {                        // row-major out: 64 rows x 8 x 16B
    const int slot = tid + p * 256;
    const int row = slot >> 3, c8 = (slot & 7) * 8;
    *(uint4*)(qr + (size_t)row * N_ + c8) = *(const uint4*)(&tile[row][c8 ^ (row & 56)]);
  }
  unsigned short* qrt = QRT + ((size_t)h * N_ + n0) * T_ + t0;
  #pragma unroll
  for (int p = 0; p < 2; p++) {                        // transposed out: 64 n-rows x 8 x 16B
    const int slot = tid + p * 256;
    const int n = slot >> 3, r8 = (slot & 7) * 8;
    __attribute__((aligned(16))) unsigned short u[8];
    #pragma unroll
    for (int i = 0; i < 8; i++) u[i] = tile[r8 + i][n ^ r8];   // (r8+i)&56 == r8
    *(uint4*)(qrt + (size_t)n * T_ + r8) = *(const uint4*)u;
  }
}

// ---------------- fp32 [Z][R][C] -> bf16 [Z][C][R], swizzled-LDS, coalesced both sides ----------------
__global__ __launch_bounds__(256) void trans2_f32_bf16(
    const float* __restrict__ src, unsigned short* __restrict__ dst,
    int R, int C)
{
  __shared__ unsigned short tile[64][64];
  const int tid = threadIdx.x;
  const int r0 = blockIdx.x * 64, c0 = blockIdx.y * 64;
  src += (size_t)blockIdx.z * R * C;
  dst += (size_t)blockIdx.z * R * C;
  #pragma unroll
  for (int p = 0; p < 4; p++) {
    const int slot = tid + p * 256;
    const int row = slot >> 4, c4 = (slot & 15) * 4;
    float4 v = *(const float4*)(src + (size_t)(r0 + row) * C + c0 + c4);
    __attribute__((aligned(8))) unsigned short u[4] =
        {f2bf(v.x), f2bf(v.y), f2bf(v.z), f2bf(v.w)};
    *(uint2*)(&tile[row][c4 ^ (row & 56)]) = *(const uint2*)u;
  }
  __syncthreads();
  #pragma unroll
  for (int p = 0; p < 2; p++) {
    const int slot = tid + p * 256;
    const int n = slot >> 3, r8 = (slot & 7) * 8;
    __attribute__((aligned(16))) unsigned short u[8];
    #pragma unroll
    for (int i = 0; i < 8; i++) u[i] = tile[r8 + i][n ^ r8];
    *(uint4*)(dst + (size_t)(c0 + n) * R + r0 + r8) = *(const uint4*)u;
  }
}

// ---------------- Kernel 2 (mega): scores(splitK4) + QR@state(splitK4) + new_state ----------------
#define NB_SC 640          // 160 lower-tri tiles x 4 K-splits (K-chunk 2048)
#define NB_OP 512          // 128 tiles x 4 K-splits
#define NB_NS 2048         // 64 n-tiles x 2 d-tiles x 16 heads, K=512
#define NB_TOT (NB_SC + NB_OP + NB_NS)   // 3200 = 8 * 400
#define OUT_STATE_OFF ((size_t)NHEAD * T_ * D_)

__global__ __launch_bounds__(256) void mega2_kernel(
    const unsigned short* __restrict__ QR, const unsigned short* __restrict__ QRT,
    const unsigned short* __restrict__ STT, const unsigned short* __restrict__ VT,
    const float* __restrict__ state, float* __restrict__ ScF, float* __restrict__ Out)
{
  __shared__ unsigned short as[128 * 32];
  __shared__ unsigned short bs[128 * 32];
  // XCD-aware swizzle (T1): 3200 % 8 == 0 -> each XCD gets a contiguous 400-block chunk
  const int blk = (blockIdx.x & 7) * (NB_TOT / 8) + (blockIdx.x >> 3);
  const int t = threadIdx.x;
  const int lane = t & 63, w = t >> 6, wr = w >> 1, wc = w & 1;
  const int q4 = (lane >> 4) * 4, rl = lane & 15;
  f32x4 acc[4][4];
  #pragma unroll
  for (int i = 0; i < 4; i++)
    #pragma unroll
    for (int j = 0; j < 4; j++) acc[i][j] = (f32x4){0.f, 0.f, 0.f, 0.f};

  if (blk < NB_SC) {
    // ---- scores partial: atomicAdd raw QR.QR^T chunk into ScF (scale/mask at consumer)
    static const int TI[10] = {0,1,1,2,2,2,3,3,3,3};
    static const int TJ[10] = {0,0,1,0,1,2,0,1,2,3};
    const int tile = blk >> 2, split = blk & 3;
    const int head = tile / 10, ti = TI[tile % 10], tj = TJ[tile % 10];
    const unsigned short* A  = QR + (size_t)head * T_ * N_ + (size_t)ti * 128 * N_;
    const unsigned short* Bp = QR + (size_t)head * T_ * N_ + (size_t)tj * 128 * N_;
    const int kbeg = split * 2048, kend = kbeg + 2048;
    for (int k0 = kbeg; k0 < kend; k0 += 32) {
      stage_direct(A + k0, N_, as, t);
      stage_direct(Bp + k0, N_, bs, t);
      __syncthreads();
      mfma_step<true, true>(as, bs, wr, wc, lane, acc);
      __syncthreads();
    }
    float* op = ScF + (size_t)head * T_ * T_;
    #pragma unroll
    for (int i = 0; i < 4; i++)
      #pragma unroll
      for (int j = 0; j < 4; j++)
        #pragma unroll
        for (int r = 0; r < 4; r++) {
          int gi = ti * 128 + wr * 64 + i * 16 + q4 + r;
          int gj = tj * 128 + wc * 64 + j * 16 + rl;
          unsafeAtomicAdd(op + (size_t)gi * T_ + gj, acc[i][j][r]);
        }
  } else if (blk < NB_SC + NB_OP) {
    // ---- out partial: QR @ state chunk via pre-transposed bf16 stateT (DMA both operands)
    const int idx = blk - NB_SC;
    const int tile = idx >> 2, split = idx & 3;
    const int head = tile >> 3, mt = (tile & 7) >> 1, nt = tile & 1;
    const unsigned short* A  = QR  + (size_t)head * T_ * N_ + (size_t)mt * 128 * N_;
    const unsigned short* Bp = STT + (size_t)head * D_ * N_ + (size_t)nt * 128 * N_;
    const int kbeg = split * 2048, kend = kbeg + 2048;
    for (int k0 = kbeg; k0 < kend; k0 += 32) {
      stage_direct(A + k0, N_, as, t);
      stage_direct(Bp + k0, N_, bs, t);
      __syncthreads();
      mfma_step<true, true>(as, bs, wr, wc, lane, acc);
      __syncthreads();
    }
    float* op = Out + (size_t)head * T_ * D_;
    #pragma unroll
    for (int i = 0; i < 4; i++)
      #pragma unroll
      for (int j = 0; j < 4; j++)
        #pragma unroll
        for (int r = 0; r < 4; r++) {
          int gi = mt * 128 + wr * 64 + i * 16 + q4 + r;
          int gj = nt * 128 + wc * 64 + j * 16 + rl;
          unsafeAtomicAdd(op + (size_t)gi * D_ + gj, acc[i][j][r]);
        }
  } else {
    // ---- new_state = state + SCALE * QR^T @ V via QRT/VT (DMA both operands)
    const int idx = blk - (NB_SC + NB_OP);
    const int head = idx >> 7, mt = (idx & 127) >> 1, nt = idx & 1;
    const unsigned short* A  = QRT + (size_t)head * N_ * T_ + (size_t)mt * 128 * T_;
    const unsigned short* Bp = VT + (size_t)(head >> 2) * D_ * T_ + (size_t)nt * 128 * T_;
    for (int k0 = 0; k0 < T_; k0 += 32) {
      stage_direct(A + k0, T_, as, t);
      stage_direct(Bp + k0, T_, bs, t);
      __syncthreads();
      mfma_step<true, true>(as, bs, wr, wc, lane, acc);
      __syncthreads();
    }
    const float* st = state + (size_t)head * N_ * D_;
    float* op = Out + OUT_STATE_OFF + (size_t)head * N_ * D_;
    #pragma unroll
    for (int i = 0; i < 4; i++)
      #pragma unroll
      for (int j = 0; j < 4; j++)
        #pragma unroll
        for (int r = 0; r < 4; r++) {
          int gm = mt * 128 + wr * 64 + i * 16 + q4 + r;
          int gd = nt * 128 + wc * 64 + j * 16 + rl;
          size_t off = (size_t)gm * D_ + gd;
          op[off] = st[off] + SCALE_ * acc[i][j][r];
        }
  }
}

// ---------------- Kernel 3: out += mask(ScF)*SCALE @ V  (splitK2, atomicAdd) ----------------
__global__ __launch_bounds__(256) void final2_kernel(
    const float* __restrict__ ScF, const unsigned short* __restrict__ VT,
    float* __restrict__ Out)
{
  __shared__ unsigned short as[128 * 40];
  __shared__ unsigned short bs[128 * 32];
  const int blk = blockIdx.x, t = threadIdx.x;
  const int lane = t & 63, w = t >> 6, wr = w >> 1, wc = w & 1;
  const int q4 = (lane >> 4) * 4, rl = lane & 15;
  const int tile = blk >> 1, split = blk & 1;
  const int head = tile >> 3, mt = (tile & 7) >> 1, nt = tile & 1;
  const float* A = ScF + (size_t)head * T_ * T_ + (size_t)mt * 128 * T_;
  const unsigned short* Bp = VT + (size_t)(head >> 2) * D_ * T_ + (size_t)nt * 128 * T_;
  f32x4 acc[4][4];
  #pragma unroll
  for (int i = 0; i < 4; i++)
    #pragma unroll
    for (int j = 0; j < 4; j++) acc[i][j] = (f32x4){0.f, 0.f, 0.f, 0.f};
  const int kbeg = split * 256, kend = kbeg + 256;
  for (int k0 = kbeg; k0 < kend; k0 += 32) {
    stage_sc(A + k0, mt * 128, k0, as, t);
    stage_direct(Bp + k0, T_, bs, t);
    __syncthreads();
    mfma_step<false, true>(as, bs, wr, wc, lane, acc);
    __syncthreads();
  }
  float* op = Out + (size_t)head * T_ * D_;
  #pragma unroll
  for (int i = 0; i < 4; i++)
    #pragma unroll
    for (int j = 0; j < 4; j++)
      #pragma unroll
      for (int r = 0; r < 4; r++) {
        int gi = mt * 128 + wr * 64 + i * 16 + q4 + r;
        int gj = nt * 128 + wc * 64 + j * 16 + rl;
        unsafeAtomicAdd(op + (size_t)gi * D_ + gj, acc[i][j][r]);
      }
}

// ws layout (bytes):
//   QR  bf16 [16][512][8192]  @ 0          (128 MiB)
//   ScF f32  [16][512][512]   @ 128 MiB    (16 MiB)
//   QRT bf16 [16][8192][512]  @ 144 MiB    (128 MiB)
//   STT bf16 [16][256][8192]  @ 272 MiB    (64 MiB)
//   VT  bf16 [4][256][512]    @ 336 MiB    (1 MiB)
#define SCF_OFF  ((size_t)134217728)
#define QRT_OFF  ((size_t)150994944)
#define STT_OFF  ((size_t)285212672)
#define VT_OFF   ((size_t)352321536)

extern "C" void kernel_launch(void* const* d_in, const int* in_sizes, int n_in,
                              void* d_out, int out_size, void* d_ws, size_t ws_size,
                              hipStream_t stream) {
  const float* Q     = (const float*)d_in[0];
  const float* V     = (const float*)d_in[1];
  const float* state = (const float*)d_in[2];
  float* out = (float*)d_out;

  unsigned short* QR  = (unsigned short*)d_ws;
  float* ScF          = (float*)((char*)d_ws + SCF_OFF);
  unsigned short* QRT = (unsigned short*)((char*)d_ws + QRT_OFF);
  unsigned short* STT = (unsigned short*)((char*)d_ws + STT_OFF);
  unsigned short* VTp = (unsigned short*)((char*)d_ws + VT_OFF);

  hipMemsetAsync(ScF, 0, (size_t)NHEAD * T_ * T_ * 4, stream);
  hipMemsetAsync(out, 0, (size_t)NHEAD * T_ * D_ * 4, stream);
  rope2_kernel<<<dim3(128, 8, 16), dim3(256), 0, stream>>>(Q, QR, QRT);
  trans2_f32_bf16<<<dim3(128, 4, 16), dim3(256), 0, stream>>>(state, STT, N_, D_);
  trans2_f32_bf16<<<dim3(8, 4, 4),    dim3(256), 0, stream>>>(V, VTp, T_, D_);
  mega2_kernel<<<dim3(NB_TOT), dim3(256), 0, stream>>>(QR, QRT, STT, VTp, state, ScF, out);
  final2_kernel<<<dim3(256), dim3(256), 0, stream>>>(ScF, VTp, out);
}

// Round 3
// 815.803 us; speedup vs baseline: 1.1629x; 1.1629x over previous
//
#include <hip/hip_runtime.h>
#include <stdint.h>

#define T_ 512
#define D_ 256
#define N_ 8192
#define NHEAD 16
#define SCALE_ 0.011048543456039806f   // 8192^-0.5
#define INV2PI 0.15915493667125702f

typedef __attribute__((ext_vector_type(8))) short bf16x8;
typedef __attribute__((ext_vector_type(4))) float f32x4;

__device__ __forceinline__ unsigned short f2bf(float x) {
  union { float f; unsigned u; } v; v.f = x;
  unsigned r = v.u + 0x7fffu + ((v.u >> 16) & 1u);   // RNE
  return (unsigned short)(r >> 16);
}

__device__ __forceinline__ void async16(const void* g, void* l) {
  __builtin_amdgcn_global_load_lds(
      (const __attribute__((address_space(1))) unsigned int*)g,
      (__attribute__((address_space(3))) unsigned int*)l,
      16, 0, 0);
}

// ---- swizzled direct staging: 128x32 bf16 tile, row-major source.
// LDS layout [128][32] linear (DMA requires), but LDS block b of row r holds
// GLOBAL block b ^ ((r>>1)&3). Fragment reads XOR-compensate -> conflict-free.
__device__ __forceinline__ void stage_direct(const unsigned short* __restrict__ g,
                                             int ld, unsigned short* lds, int t) {
  const int row = t >> 2, b = t & 3;
  const int g1 = (b ^ ((row >> 1) & 3)) * 8;
  async16(g + (size_t)row * ld + g1, lds + row * 32 + b * 8);
  const int row2 = row + 64;
  const int g2 = (b ^ ((row2 >> 1) & 3)) * 8;
  async16(g + (size_t)row2 * ld + g2, lds + row2 * 32 + b * 8);
}

// ---- fp32 row-major staging with fused scale + strict-tril mask (scores A operand)
__device__ __forceinline__ void stage_sc(const float* __restrict__ g, int gi0, int gk0,
                                         unsigned short* lds, int t) {
  const int row = t >> 2, c8 = (t & 3) * 8;
  #pragma unroll
  for (int rr = 0; rr < 2; rr++) {
    const int r = row + rr * 64;
    const float* p = g + (size_t)r * T_ + c8;
    float4 x = *(const float4*)p, y = *(const float4*)(p + 4);
    float f[8] = {x.x, x.y, x.z, x.w, y.x, y.y, y.z, y.w};
    const int gi = gi0 + r;
    __attribute__((aligned(16))) unsigned short u[8];
    #pragma unroll
    for (int e = 0; e < 8; e++) {
      float v = ((gk0 + c8 + e) < gi) ? f[e] * SCALE_ : 0.f;
      u[e] = f2bf(v);
    }
    *(uint4*)(lds + r * 40 + c8) = *(const uint4*)u;
  }
}

// One BK=32 step: wave (wr,wc) computes 64x64 of the 128x128 C tile.
// SWA/SWB: operand uses swizzled-[128][32] layout (else padded-[128][40]).
template<bool SWA, bool SWB>
__device__ __forceinline__ void mfma_step(const unsigned short* as, const unsigned short* bs,
                                          int wr, int wc, int lane, f32x4 acc[4][4]) {
  const int j8 = lane >> 4, rl = lane & 15;
  const int swz = (j8 ^ ((rl >> 1) & 3)) * 8;   // row base %16==0 -> s(row)=(rl>>1)&3
  const int pad = j8 * 8;
  bf16x8 a[4], b[4];
  #pragma unroll
  for (int i = 0; i < 4; i++) {
    int r = wr * 64 + i * 16 + rl;
    a[i] = SWA ? *(const bf16x8*)(as + r * 32 + swz)
               : *(const bf16x8*)(as + r * 40 + pad);
  }
  #pragma unroll
  for (int j = 0; j < 4; j++) {
    int r = wc * 64 + j * 16 + rl;
    b[j] = SWB ? *(const bf16x8*)(bs + r * 32 + swz)
               : *(const bf16x8*)(bs + r * 40 + pad);
  }
  #pragma unroll
  for (int i = 0; i < 4; i++)
    #pragma unroll
    for (int j = 0; j < 4; j++)
      acc[i][j] = __builtin_amdgcn_mfma_f32_16x16x32_bf16(a[i], b[j], acc[i][j], 0, 0, 0);
}

// ---------------- Kernel 1: fused rope -> QR (row-major) AND QRT (transposed) ----------------
__global__ __launch_bounds__(256) void rope2_kernel(
    const float* __restrict__ Q, unsigned short* __restrict__ QR,
    unsigned short* __restrict__ QRT)
{
  __shared__ unsigned short tile[64][64];
  const int tid = threadIdx.x;
  const int n0 = blockIdx.x * 64, t0 = blockIdx.y * 64, h = blockIdx.z;
  const float* src = Q + ((size_t)h * T_ + t0) * N_ + n0;
  #pragma unroll
  for (int p = 0; p < 4; p++) {                        // 1024 slots: 64 rows x 16 x (4 f32)
    const int slot = tid + p * 256;
    const int row = slot >> 4, c4 = (slot & 15) * 4;
    float4 v = *(const float4*)(src + (size_t)row * N_ + c4);
    const float ft = (float)(t0 + row);
    __attribute__((aligned(8))) unsigned short u[4];
    #pragma unroll
    for (int pp = 0; pp < 2; pp++) {
      const int m = ((n0 + c4) >> 1) + pp;             // floor(idx/2)
      float f = exp2f((float)m * (-1.0f / 256.0f)) * INV2PI;
      float r = ft * f;
      r = r - floorf(r);                               // phases mod 1
      float cs = __builtin_amdgcn_cosf(r);             // cos(2*pi*r)
      float sn = __builtin_amdgcn_sinf(r);
      float ev = (pp == 0) ? v.x : v.z;
      float od = (pp == 0) ? v.y : v.w;
      u[2 * pp]     = f2bf(ev * cs - od * sn);
      u[2 * pp + 1] = f2bf(od * cs + ev * sn);
    }
    *(uint2*)(&tile[row][c4 ^ (row & 56)]) = *(const uint2*)u;
  }
  __syncthreads();
  unsigned short* qr = QR + ((size_t)h * T_ + t0) * N_ + n0;
  #pragma unroll
  for (int p = 0; p < 2; p++) {                        // row-major out: 64 rows x 8 x 16B
    const int slot = tid + p * 256;
    const int row = slot >> 3, c8 = (slot & 7) * 8;
    *(uint4*)(qr + (size_t)row * N_ + c8) = *(const uint4*)(&tile[row][c8 ^ (row & 56)]);
  }
  unsigned short* qrt = QRT + ((size_t)h * N_ + n0) * T_ + t0;
  #pragma unroll
  for (int p = 0; p < 2; p++) {                        // transposed out: 64 n-rows x 8 x 16B
    const int slot = tid + p * 256;
    const int n = slot >> 3, r8 = (slot & 7) * 8;
    __attribute__((aligned(16))) unsigned short u[8];
    #pragma unroll
    for (int i = 0; i < 8; i++) u[i] = tile[r8 + i][n ^ r8];   // (r8+i)&56 == r8
    *(uint4*)(qrt + (size_t)n * T_ + r8) = *(const uint4*)u;
  }
}

// ---------------- fp32 [Z][R][C] -> bf16 [Z][C][R], swizzled-LDS, coalesced both sides ----------------
__global__ __launch_bounds__(256) void trans2_f32_bf16(
    const float* __restrict__ src, unsigned short* __restrict__ dst,
    int R, int C)
{
  __shared__ unsigned short tile[64][64];
  const int tid = threadIdx.x;
  const int r0 = blockIdx.x * 64, c0 = blockIdx.y * 64;
  src += (size_t)blockIdx.z * R * C;
  dst += (size_t)blockIdx.z * R * C;
  #pragma unroll
  for (int p = 0; p < 4; p++) {
    const int slot = tid + p * 256;
    const int row = slot >> 4, c4 = (slot & 15) * 4;
    float4 v = *(const float4*)(src + (size_t)(r0 + row) * C + c0 + c4);
    __attribute__((aligned(8))) unsigned short u[4] =
        {f2bf(v.x), f2bf(v.y), f2bf(v.z), f2bf(v.w)};
    *(uint2*)(&tile[row][c4 ^ (row & 56)]) = *(const uint2*)u;
  }
  __syncthreads();
  #pragma unroll
  for (int p = 0; p < 2; p++) {
    const int slot = tid + p * 256;
    const int n = slot >> 3, r8 = (slot & 7) * 8;
    __attribute__((aligned(16))) unsigned short u[8];
    #pragma unroll
    for (int i = 0; i < 8; i++) u[i] = tile[r8 + i][n ^ r8];
    *(uint4*)(dst + (size_t)(c0 + n) * R + r0 + r8) = *(const uint4*)u;
  }
}

// ---------------- Kernel 2 (mega): scores(splitK4) + QR@state(splitK4) + new_state ----------------
#define NB_SC 640          // 160 lower-tri tiles x 4 K-splits (K-chunk 2048)
#define NB_OP 512          // 128 tiles x 4 K-splits
#define NB_NS 2048         // 64 n-tiles x 2 d-tiles x 16 heads, K=512
#define NB_TOT (NB_SC + NB_OP + NB_NS)
#define OUT_STATE_OFF ((size_t)NHEAD * T_ * D_)

__global__ __launch_bounds__(256) void mega2_kernel(
    const unsigned short* __restrict__ QR, const unsigned short* __restrict__ QRT,
    const unsigned short* __restrict__ STT, const unsigned short* __restrict__ VT,
    const float* __restrict__ state, float* __restrict__ ScF, float* __restrict__ Out)
{
  __shared__ unsigned short as[128 * 32];
  __shared__ unsigned short bs[128 * 32];
  // Per-segment XCD chunking: each XCD gets a contiguous chunk WITHIN each
  // homogeneous segment -> L2 locality AND balanced work mix per XCD.
  const int bid = blockIdx.x;
  int blk;
  if (bid < NB_SC) {
    blk = (bid & 7) * (NB_SC / 8) + (bid >> 3);
  } else if (bid < NB_SC + NB_OP) {
    const int i = bid - NB_SC;
    blk = NB_SC + (i & 7) * (NB_OP / 8) + (i >> 3);
  } else {
    const int i = bid - (NB_SC + NB_OP);
    blk = NB_SC + NB_OP + (i & 7) * (NB_NS / 8) + (i >> 3);
  }
  const int t = threadIdx.x;
  const int lane = t & 63, w = t >> 6, wr = w >> 1, wc = w & 1;
  const int q4 = (lane >> 4) * 4, rl = lane & 15;
  f32x4 acc[4][4];
  #pragma unroll
  for (int i = 0; i < 4; i++)
    #pragma unroll
    for (int j = 0; j < 4; j++) acc[i][j] = (f32x4){0.f, 0.f, 0.f, 0.f};

  if (blk < NB_SC) {
    // ---- scores partial: atomicAdd raw QR.QR^T chunk into ScF (scale/mask at consumer)
    static const int TI[10] = {0,1,1,2,2,2,3,3,3,3};
    static const int TJ[10] = {0,0,1,0,1,2,0,1,2,3};
    const int tile = blk >> 2, split = blk & 3;
    const int head = tile / 10, ti = TI[tile % 10], tj = TJ[tile % 10];
    const unsigned short* A  = QR + (size_t)head * T_ * N_ + (size_t)ti * 128 * N_;
    const unsigned short* Bp = QR + (size_t)head * T_ * N_ + (size_t)tj * 128 * N_;
    const int kbeg = split * 2048, kend = kbeg + 2048;
    for (int k0 = kbeg; k0 < kend; k0 += 32) {
      stage_direct(A + k0, N_, as, t);
      stage_direct(Bp + k0, N_, bs, t);
      __syncthreads();
      mfma_step<true, true>(as, bs, wr, wc, lane, acc);
      __syncthreads();
    }
    float* op = ScF + (size_t)head * T_ * T_;
    #pragma unroll
    for (int i = 0; i < 4; i++)
      #pragma unroll
      for (int j = 0; j < 4; j++)
        #pragma unroll
        for (int r = 0; r < 4; r++) {
          int gi = ti * 128 + wr * 64 + i * 16 + q4 + r;
          int gj = tj * 128 + wc * 64 + j * 16 + rl;
          unsafeAtomicAdd(op + (size_t)gi * T_ + gj, acc[i][j][r]);
        }
  } else if (blk < NB_SC + NB_OP) {
    // ---- out partial: QR @ state chunk via pre-transposed bf16 stateT (DMA both operands)
    const int idx = blk - NB_SC;
    const int tile = idx >> 2, split = idx & 3;
    const int head = tile >> 3, mt = (tile & 7) >> 1, nt = tile & 1;
    const unsigned short* A  = QR  + (size_t)head * T_ * N_ + (size_t)mt * 128 * N_;
    const unsigned short* Bp = STT + (size_t)head * D_ * N_ + (size_t)nt * 128 * N_;
    const int kbeg = split * 2048, kend = kbeg + 2048;
    for (int k0 = kbeg; k0 < kend; k0 += 32) {
      stage_direct(A + k0, N_, as, t);
      stage_direct(Bp + k0, N_, bs, t);
      __syncthreads();
      mfma_step<true, true>(as, bs, wr, wc, lane, acc);
      __syncthreads();
    }
    float* op = Out + (size_t)head * T_ * D_;
    #pragma unroll
    for (int i = 0; i < 4; i++)
      #pragma unroll
      for (int j = 0; j < 4; j++)
        #pragma unroll
        for (int r = 0; r < 4; r++) {
          int gi = mt * 128 + wr * 64 + i * 16 + q4 + r;
          int gj = nt * 128 + wc * 64 + j * 16 + rl;
          unsafeAtomicAdd(op + (size_t)gi * D_ + gj, acc[i][j][r]);
        }
  } else {
    // ---- new_state = state + SCALE * QR^T @ V via QRT/VT (DMA both operands)
    const int idx = blk - (NB_SC + NB_OP);
    const int head = idx >> 7, mt = (idx & 127) >> 1, nt = idx & 1;
    const unsigned short* A  = QRT + (size_t)head * N_ * T_ + (size_t)mt * 128 * T_;
    const unsigned short* Bp = VT + (size_t)(head >> 2) * D_ * T_ + (size_t)nt * 128 * T_;
    for (int k0 = 0; k0 < T_; k0 += 32) {
      stage_direct(A + k0, T_, as, t);
      stage_direct(Bp + k0, T_, bs, t);
      __syncthreads();
      mfma_step<true, true>(as, bs, wr, wc, lane, acc);
      __syncthreads();
    }
    const float* st = state + (size_t)head * N_ * D_;
    float* op = Out + OUT_STATE_OFF + (size_t)head * N_ * D_;
    #pragma unroll
    for (int i = 0; i < 4; i++)
      #pragma unroll
      for (int j = 0; j < 4; j++)
        #pragma unroll
        for (int r = 0; r < 4; r++) {
          int gm = mt * 128 + wr * 64 + i * 16 + q4 + r;
          int gd = nt * 128 + wc * 64 + j * 16 + rl;
          size_t off = (size_t)gm * D_ + gd;
          op[off] = st[off] + SCALE_ * acc[i][j][r];
        }
  }
}

// ---------------- Kernel 3: out += mask(ScF)*SCALE @ V  (splitK4, atomicAdd) ----------------
__global__ __launch_bounds__(256) void final2_kernel(
    const float* __restrict__ ScF, const unsigned short* __restrict__ VT,
    float* __restrict__ Out)
{
  __shared__ unsigned short as[128 * 40];
  __shared__ unsigned short bs[128 * 32];
  const int blk = blockIdx.x, t = threadIdx.x;
  const int lane = t & 63, w = t >> 6, wr = w >> 1, wc = w & 1;
  const int q4 = (lane >> 4) * 4, rl = lane & 15;
  const int tile = blk >> 2, split = blk & 3;
  const int head = tile >> 3, mt = (tile & 7) >> 1, nt = tile & 1;
  const float* A = ScF + (size_t)head * T_ * T_ + (size_t)mt * 128 * T_;
  const unsigned short* Bp = VT + (size_t)(head >> 2) * D_ * T_ + (size_t)nt * 128 * T_;
  f32x4 acc[4][4];
  #pragma unroll
  for (int i = 0; i < 4; i++)
    #pragma unroll
    for (int j = 0; j < 4; j++) acc[i][j] = (f32x4){0.f, 0.f, 0.f, 0.f};
  const int kbeg = split * 128, kend = kbeg + 128;
  for (int k0 = kbeg; k0 < kend; k0 += 32) {
    stage_sc(A + k0, mt * 128, k0, as, t);
    stage_direct(Bp + k0, T_, bs, t);
    __syncthreads();
    mfma_step<false, true>(as, bs, wr, wc, lane, acc);
    __syncthreads();
  }
  float* op = Out + (size_t)head * T_ * D_;
  #pragma unroll
  for (int i = 0; i < 4; i++)
    #pragma unroll
    for (int j = 0; j < 4; j++)
      #pragma unroll
      for (int r = 0; r < 4; r++) {
        int gi = mt * 128 + wr * 64 + i * 16 + q4 + r;
        int gj = nt * 128 + wc * 64 + j * 16 + rl;
        unsafeAtomicAdd(op + (size_t)gi * D_ + gj, acc[i][j][r]);
      }
}

// ws layout (bytes):
//   QR  bf16 [16][512][8192]  @ 0          (128 MiB)
//   ScF f32  [16][512][512]   @ 128 MiB    (16 MiB)
//   QRT bf16 [16][8192][512]  @ 144 MiB    (128 MiB)
//   STT bf16 [16][256][8192]  @ 272 MiB    (64 MiB)
//   VT  bf16 [4][256][512]    @ 336 MiB    (1 MiB)
#define SCF_OFF  ((size_t)134217728)
#define QRT_OFF  ((size_t)150994944)
#define STT_OFF  ((size_t)285212672)
#define VT_OFF   ((size_t)352321536)

extern "C" void kernel_launch(void* const* d_in, const int* in_sizes, int n_in,
                              void* d_out, int out_size, void* d_ws, size_t ws_size,
                              hipStream_t stream) {
  const float* Q     = (const float*)d_in[0];
  const float* V     = (const float*)d_in[1];
  const float* state = (const float*)d_in[2];
  float* out = (float*)d_out;

  unsigned short* QR  = (unsigned short*)d_ws;
  float* ScF          = (float*)((char*)d_ws + SCF_OFF);
  unsigned short* QRT = (unsigned short*)((char*)d_ws + QRT_OFF);
  unsigned short* STT = (unsigned short*)((char*)d_ws + STT_OFF);
  unsigned short* VTp = (unsigned short*)((char*)d_ws + VT_OFF);

  hipMemsetAsync(ScF, 0, (size_t)NHEAD * T_ * T_ * 4, stream);
  hipMemsetAsync(out, 0, (size_t)NHEAD * T_ * D_ * 4, stream);
  rope2_kernel<<<dim3(128, 8, 16), dim3(256), 0, stream>>>(Q, QR, QRT);
  trans2_f32_bf16<<<dim3(128, 4, 16), dim3(256), 0, stream>>>(state, STT, N_, D_);
  trans2_f32_bf16<<<dim3(8, 4, 4),    dim3(256), 0, stream>>>(V, VTp, T_, D_);
  mega2_kernel<<<dim3(NB_TOT), dim3(256), 0, stream>>>(QR, QRT, STT, VTp, state, ScF, out);
  final2_kernel<<<dim3(512), dim3(256), 0, stream>>>(ScF, VTp, out);
}